// Round 2
// baseline (350.635 us; speedup 1.0000x reference)
//
#include <hip/hip_runtime.h>
#include <stdint.h>

// Problem constants: B=4, C=128, H=W=128, N=9, OC=256, stride=1
#define CIN   128
#define HWSZ  16384
#define NP    9
#define OCH   256
#define KDIM  1152   // 9*128
#define NK8   144    // KDIM/8

typedef __bf16 bf16_t;
typedef __bf16 bf16x8 __attribute__((ext_vector_type(8)));
typedef float  f32x4  __attribute__((ext_vector_type(4)));
struct __attribute__((packed, aligned(4))) F2 { float x, y; };

// ---------------------------------------------------------------------------
// B repack: bt[k8][o][8] bf16 (MFMA B-fragment order). k = k8*8+i = n*128+c.
// ---------------------------------------------------------------------------
__global__ void k_bt(const float* __restrict__ wc, bf16_t* __restrict__ bt) {
  int k8 = blockIdx.x, og = blockIdx.y, tid = threadIdx.x;
  int i = tid & 7, o = og * 32 + (tid >> 3);
  int k = k8 * 8 + i, c = k & 127, n = k >> 7;
  bt[(size_t)k8 * 2048 + og * 256 + tid] = (bf16_t)wc[(o * CIN + c) * NP + n];
}

// ---------------------------------------------------------------------------
// Offset conv partials, split-K over NSPLIT blocks per (b,ii).
// fp32 REQUIRED (bilinear discontinuity at integer boundaries).
// 256 threads = 128 j x 2 c-halves; x rows staged in LDS (double-buffered)
// so global loads drop 6x vs per-thread 3x3 reads.
// ---------------------------------------------------------------------------
template<int NSPLIT>
__global__ __launch_bounds__(256, 6) void k_conv_part(
    const float* __restrict__ x, const float* __restrict__ wp,
    float* __restrict__ part)
{
  constexpr int CPT = CIN / NSPLIT;   // channels per block
  constexpr int CH  = CPT / 2;        // channels per chalf
  constexpr int NBLK = 512 * NSPLIT;
  int blk = (blockIdx.x & 7) * (NBLK >> 3) + (blockIdx.x >> 3);  // XCD swizzle
  int bbii = blk / NSPLIT, cq = blk % NSPLIT;
  int bb = bbii >> 7, ii = bbii & 127;
  int tid = threadIdx.x;
  int j = tid & 127, chalf = tid >> 7;
  int cbase = cq * CPT;

  __shared__ float st[2][2][3][132];   // [buf][ch][row][col+pad]
  __shared__ float red[128][18];

  float acc[18];
#pragma unroll
  for (int o = 0; o < 18; ++o) acc[o] = 0.f;

  auto stage = [&](int it, int buf) {
    for (int t = tid; t < 792; t += 256) {
      int ch = t / 396, rem = t % 396;
      int r = rem / 132, cc = rem % 132;
      int c = cbase + ch * CH + it;
      int ir = ii + r - 1, ic = cc - 1;
      float v = 0.f;
      if ((unsigned)ir < 128u && (unsigned)ic < 128u)
        v = x[(size_t)(bb * CIN + c) * HWSZ + ir * 128 + ic];
      st[buf][ch][r][cc] = v;
    }
  };

  stage(0, 0);
  for (int it = 0; it < CH; ++it) {
    __syncthreads();                       // stage(it) visible; prev reads done
    if (it + 1 < CH) stage(it + 1, (it + 1) & 1);
    int c = cbase + chalf * CH + it;       // wave-uniform
    int cu = __builtin_amdgcn_readfirstlane(c);
    const float* wr = wp + cu * 9;         // sgpr weight base
    float xv[9];
#pragma unroll
    for (int dy = 0; dy < 3; ++dy)
#pragma unroll
      for (int dx = 0; dx < 3; ++dx)
        xv[dy * 3 + dx] = st[it & 1][chalf][dy][j + dx];
#pragma unroll
    for (int o = 0; o < 18; ++o)
#pragma unroll
      for (int t = 0; t < 9; ++t)
        acc[o] += xv[t] * wr[o * KDIM + t];
  }

  if (chalf == 1) {
#pragma unroll
    for (int o = 0; o < 18; ++o) red[j][o] = acc[o];
  }
  __syncthreads();
  if (chalf == 0) {
#pragma unroll
    for (int o = 0; o < 18; ++o) acc[o] += red[j][o];
    float* pp = part + (size_t)(bbii * NSPLIT + cq) * 18 * 128;
#pragma unroll
    for (int o = 0; o < 18; ++o) pp[o * 128 + j] = acc[o];
  }
}

// ---------------------------------------------------------------------------
// Reduce partials + bilinear meta (pre-selected weights A,B,C,D).
// ---------------------------------------------------------------------------
template<int NSPLIT>
__global__ void k_meta(const float* __restrict__ part, const float* __restrict__ bp,
                       int* __restrict__ midx, float4* __restrict__ mw)
{
  int blk = blockIdx.x;                 // bb*128+ii
  int ii = blk & 127;
  int j = threadIdx.x;                  // 128
  float acc[18];
#pragma unroll
  for (int o = 0; o < 18; ++o) {
    float s = 0.f;
#pragma unroll
    for (int cq = 0; cq < NSPLIT; ++cq)
      s += part[((size_t)(blk * NSPLIT + cq) * 18 + o) * 128 + j];
    acc[o] = s;
  }
#pragma unroll
  for (int n = 0; n < NP; ++n) {
    float offx = acc[n] + bp[n];
    float offy = acc[9 + n] + bp[9 + n];
    float px = (float)ii + (float)(n / 3) + offx;
    float py = (float)j  + (float)(n % 3) + offy;
    float f0 = floorf(px), f1 = f0 + 1.f;
    float h0 = floorf(py), h1 = h0 + 1.f;
    int r0 = (int)fminf(fmaxf(f0, 0.f), 127.f);
    int r1 = (int)fminf(fmaxf(f1, 0.f), 127.f);
    int c0 = (int)fminf(fmaxf(h0, 0.f), 127.f);
    int c1 = (int)fminf(fmaxf(h1, 0.f), 127.f);
    float pxc = fminf(fmaxf(px, 0.f), 127.f);
    float pyc = fminf(fmaxf(py, 0.f), 127.f);
    float glt = (1.f + ((float)r0 - pxc)) * (1.f + ((float)c0 - pyc));
    float grb = (1.f - ((float)r1 - pxc)) * (1.f - ((float)c1 - pyc));
    float glb = (1.f + ((float)r0 - pxc)) * (1.f - ((float)c1 - pyc));
    float grt = (1.f - ((float)r1 - pxc)) * (1.f + ((float)c0 - pyc));
    int qb = (c0 < 126) ? c0 : 126;
    bool s0 = (c0 != qb), s1 = (c1 != qb);
    float wA = (s0 ? 0.f : glt) + (s1 ? 0.f : glb);
    float wB = (s0 ? glt : 0.f) + (s1 ? glb : 0.f);
    float wC = (s0 ? 0.f : grt) + (s1 ? 0.f : grb);
    float wD = (s0 ? grt : 0.f) + (s1 ? grb : 0.f);
    int base = (blk * NP + n) * 128 + j;
    midx[base] = r0 | (r1 << 8) | (qb << 16);
    mw[base] = make_float4(wA, wB, wC, wD);
  }
}

// ---------------------------------------------------------------------------
// Two-phase gather+GEMM. Block = (b, ii, j-quarter): M=32, N=256, K=1152.
// Phase 1 (no barriers): gather A[32j][1152k] -> LDS, k8-block-major
//   A[k8][j][8] so each av8 is one ds_write_b128 and wave writes are 1KB
//   contiguous (conflict-free, no swizzle needed).
// Phase 2 (one barrier, then none): 8 waves x 32 o each; per step (BK=32):
//   2 ds_read_b128 A-frags + 2 global 16B B-frags (bt L2-resident,
//   prefetched 1 step) + 4 MFMA. acc stays in 16 VGPRs.
// 73,728 B LDS -> 2 blocks/CU; block A's phase-1 overlaps block B's phase-2.
// ---------------------------------------------------------------------------
__global__ __launch_bounds__(512, 4) void k_gg(
    const float* __restrict__ x, const bf16_t* __restrict__ bt,
    const int* __restrict__ midx, const float4* __restrict__ mw,
    float* __restrict__ out)
{
  __shared__ __align__(16) bf16_t A[NK8 * 32 * 8];   // 73,728 B
  int blk = (blockIdx.x & 7) * 256 + (blockIdx.x >> 3);  // XCD swizzle (2048)
  int bb = blk >> 9, ii = (blk >> 2) & 127, jq = blk & 3;
  int tid = threadIdx.x;

  // ---- phase 1: gather
  {
    int j = tid & 31, cg = tid >> 5;            // cg = c8-block 0..15
    int jglob = jq * 32 + j;
    int mbase = (bb * 128 + ii) * KDIM;
    const float* xb = x + (size_t)bb * CIN * HWSZ + (size_t)cg * 8 * HWSZ;
#pragma unroll 3
    for (int n = 0; n < NP; ++n) {
      int idx = midx[mbase + n * 128 + jglob];
      float4 wv = mw[mbase + n * 128 + jglob];
      int r0 = idx & 255, r1 = (idx >> 8) & 255, qb = (idx >> 16) & 255;
      int oA = (r0 << 7) + qb, oB = (r1 << 7) + qb;
      bf16x8 av;
#pragma unroll
      for (int it = 0; it < 8; ++it) {
        const float* p = xb + (size_t)it * HWSZ;
        F2 pa = *(const F2*)(p + oA);   // row r0: cols qb, qb+1
        F2 pb = *(const F2*)(p + oB);   // row r1
        av[it] = (bf16_t)(wv.x * pa.x + wv.y * pa.y + wv.z * pb.x + wv.w * pb.y);
      }
      *(bf16x8*)(A + ((n * 16 + cg) * 32 + j) * 8) = av;
    }
  }
  __syncthreads();

  // ---- phase 2: GEMM
  int wave = tid >> 6, lane = tid & 63;
  int l15 = lane & 15, quad = lane >> 4;
  int wo = wave * 32;
  const bf16_t* bq = bt + (size_t)quad * 2048 + (wo + l15) * 8;

  f32x4 acc00 = (f32x4){0.f,0.f,0.f,0.f}, acc01 = acc00, acc10 = acc00, acc11 = acc00;

  bf16x8 bc0 = *(const bf16x8*)(bq);
  bf16x8 bc1 = *(const bf16x8*)(bq + 128);
#pragma unroll 2
  for (int step = 0; step < 36; ++step) {
    bf16x8 bn0 = bc0, bn1 = bc1;
    if (step < 35) {
      bn0 = *(const bf16x8*)(bq + (size_t)(step + 1) * 8192);
      bn1 = *(const bf16x8*)(bq + (size_t)(step + 1) * 8192 + 128);
    }
    bf16x8 af0 = *(bf16x8*)(A + ((step * 4 + quad) * 32 + l15) * 8);
    bf16x8 af1 = *(bf16x8*)(A + ((step * 4 + quad) * 32 + 16 + l15) * 8);
    acc00 = __builtin_amdgcn_mfma_f32_16x16x32_bf16(af0, bc0, acc00, 0, 0, 0);
    acc10 = __builtin_amdgcn_mfma_f32_16x16x32_bf16(af1, bc0, acc10, 0, 0, 0);
    acc01 = __builtin_amdgcn_mfma_f32_16x16x32_bf16(af0, bc1, acc01, 0, 0, 0);
    acc11 = __builtin_amdgcn_mfma_f32_16x16x32_bf16(af1, bc1, acc11, 0, 0, 0);
    bc0 = bn0; bc1 = bn1;
  }
  __syncthreads();   // all waves done reading A; safe to reuse as epilogue LDS

  // ---- epilogue: per-wave transpose [32o][32j] through LDS, coalesced stores
  float* piece = (float*)A + wave * (32 * 36);   // 36-float rows (16B-aligned)
  *(f32x4*)(piece + (l15     ) * 36 + quad * 4     ) = acc00;
  *(f32x4*)(piece + (l15     ) * 36 + 16 + quad * 4) = acc10;
  *(f32x4*)(piece + (16 + l15) * 36 + quad * 4     ) = acc01;
  *(f32x4*)(piece + (16 + l15) * 36 + 16 + quad * 4) = acc11;
  // wave-local RAW: compiler orders via lgkmcnt dependence
#pragma unroll
  for (int g = 0; g < 4; ++g) {
    int o_loc = g * 8 + (lane >> 3), jj = (lane & 7) * 4;
    f32x4 v = *(f32x4*)(piece + o_loc * 36 + jj);
    *(f32x4*)(out + ((size_t)(bb * OCH + wo + o_loc) * 128 + ii) * 128 + jq * 32 + jj) = v;
  }
}

// ---------------------------------------------------------------------------
extern "C" void kernel_launch(void* const* d_in, const int* in_sizes, int n_in,
                              void* d_out, int out_size, void* d_ws, size_t ws_size,
                              hipStream_t stream) {
  const float* x  = (const float*)d_in[0];
  const float* wp = (const float*)d_in[1];
  const float* bp = (const float*)d_in[2];
  const float* wc = (const float*)d_in[3];
  float* out = (float*)d_out;

  bf16_t* BT   = (bf16_t*)d_ws;                               //   589,824 B
  int*    MIDX = (int*)   ((char*)d_ws + (1u  << 20));        // 2,359,296 B
  float4* MW   = (float4*)((char*)d_ws + (4u  << 20));        // 9,437,184 B
  float*  PART = (float*) ((char*)d_ws + (14u << 20));        // up to 18.9 MB

  k_bt<<<dim3(NK8, 8), 256, 0, stream>>>(wc, BT);
  if (ws_size >= (33u << 20)) {
    k_conv_part<4><<<2048, 256, 0, stream>>>(x, wp, PART);
    k_meta<4><<<512, 128, 0, stream>>>(PART, bp, MIDX, MW);
  } else {
    k_conv_part<1><<<512, 256, 0, stream>>>(x, wp, PART);
    k_meta<1><<<512, 128, 0, stream>>>(PART, bp, MIDX, MW);
  }
  k_gg<<<2048, 512, 0, stream>>>(x, BT, MIDX, MW, out);
}

// Round 3
// 295.133 us; speedup vs baseline: 1.1881x; 1.1881x over previous
//
#include <hip/hip_runtime.h>
#include <stdint.h>

// Problem constants: B=4, C=128, H=W=128, N=9, OC=256, stride=1
#define CIN   128
#define HWSZ  16384
#define NP    9
#define OCH   256
#define KP    1280        // padded K: k' = (c/16)*160 + n*16 + (c%16), n 0..9 (n=9 zero)
#define NSLICE 40         // KP/32 K32-steps

typedef __bf16 bf16_t;
typedef __bf16 bf16x8 __attribute__((ext_vector_type(8)));
typedef float  f32x4  __attribute__((ext_vector_type(4)));
typedef _Float16 f16x4 __attribute__((ext_vector_type(4)));
union MU { uint2 u; f16x4 h; };
struct __attribute__((packed, aligned(4))) F2 { float x, y; };

// async global->LDS, 16B per lane; LDS dest must be wave-uniform base + lane*16.
__device__ __forceinline__ void gll16(const void* g, void* l) {
  __builtin_amdgcn_global_load_lds(
      (const __attribute__((address_space(1))) void*)g,
      (__attribute__((address_space(3))) void*)l, 16, 0, 0);
}

// ---------------------------------------------------------------------------
// B repack, padded fragment order: bt[k8'][o][8] bf16, k8' in [0,160).
// k' = k8'*8+i; cc = k'/160; n = (k'%160)>>4; ci = k'%16; c = cc*16+ci.
// n==9 is zero padding (A side is zeroed too).
// ---------------------------------------------------------------------------
__global__ void k_bt(const float* __restrict__ wc, bf16_t* __restrict__ bt) {
  int k8 = blockIdx.x, og = blockIdx.y, tid = threadIdx.x;
  int i = tid & 7, o = og * 32 + (tid >> 3);
  int kp = k8 * 8 + i;
  int cc = kp / 160, rem = kp % 160;
  int n = rem >> 4, ci = rem & 15;
  int c = cc * 16 + ci;
  float v = (n < 9) ? wc[(o * CIN + c) * NP + n] : 0.f;
  bt[(size_t)k8 * 2048 + o * 8 + i] = (bf16_t)v;
}

// ---------------------------------------------------------------------------
// Offset conv partials, split-K over NSPLIT blocks per (b,ii). fp32 REQUIRED.
// ---------------------------------------------------------------------------
template<int NSPLIT>
__global__ __launch_bounds__(256, 6) void k_conv_part(
    const float* __restrict__ x, const float* __restrict__ wp,
    float* __restrict__ part)
{
  constexpr int CPT = CIN / NSPLIT;
  constexpr int CH  = CPT / 2;
  constexpr int NBLK = 512 * NSPLIT;
  int blk = (blockIdx.x & 7) * (NBLK >> 3) + (blockIdx.x >> 3);  // XCD swizzle
  int bbii = blk / NSPLIT, cq = blk % NSPLIT;
  int bb = bbii >> 7, ii = bbii & 127;
  int tid = threadIdx.x;
  int j = tid & 127, chalf = tid >> 7;
  int cbase = cq * CPT;

  __shared__ float st[2][2][3][132];
  __shared__ float red[128][18];

  float acc[18];
#pragma unroll
  for (int o = 0; o < 18; ++o) acc[o] = 0.f;

  auto stage = [&](int it, int buf) {
    for (int t = tid; t < 792; t += 256) {
      int ch = t / 396, rem = t % 396;
      int r = rem / 132, cc = rem % 132;
      int c = cbase + ch * CH + it;
      int ir = ii + r - 1, ic = cc - 1;
      float v = 0.f;
      if ((unsigned)ir < 128u && (unsigned)ic < 128u)
        v = x[(size_t)(bb * CIN + c) * HWSZ + ir * 128 + ic];
      st[buf][ch][r][cc] = v;
    }
  };

  stage(0, 0);
  for (int it = 0; it < CH; ++it) {
    __syncthreads();
    if (it + 1 < CH) stage(it + 1, (it + 1) & 1);
    int c = cbase + chalf * CH + it;
    int cu = __builtin_amdgcn_readfirstlane(c);
    const float* wr = wp + cu * 9;
    float xv[9];
#pragma unroll
    for (int dy = 0; dy < 3; ++dy)
#pragma unroll
      for (int dx = 0; dx < 3; ++dx)
        xv[dy * 3 + dx] = st[it & 1][chalf][dy][j + dx];
#pragma unroll
    for (int o = 0; o < 18; ++o)
#pragma unroll
      for (int t = 0; t < 9; ++t)
        acc[o] += xv[t] * wr[o * (CIN * 9) + t];
  }

  if (chalf == 1) {
#pragma unroll
    for (int o = 0; o < 18; ++o) red[j][o] = acc[o];
  }
  __syncthreads();
  if (chalf == 0) {
#pragma unroll
    for (int o = 0; o < 18; ++o) acc[o] += red[j][o];
    float* pp = part + (size_t)(bbii * NSPLIT + cq) * 18 * 128;
#pragma unroll
    for (int o = 0; o < 18; ++o) pp[o * 128 + j] = acc[o];
  }
}

// ---------------------------------------------------------------------------
// Reduce partials + bilinear meta. Weights packed as 4 x f16 (err 2^-11,
// far below the bf16 GEMM rounding) -> meta fits proven workspace w/o branch.
// ---------------------------------------------------------------------------
template<int NSPLIT>
__global__ void k_meta(const float* __restrict__ part, const float* __restrict__ bp,
                       int* __restrict__ midx, uint2* __restrict__ mwh)
{
  int blk = blockIdx.x;
  int ii = blk & 127;
  int j = threadIdx.x;
  float acc[18];
#pragma unroll
  for (int o = 0; o < 18; ++o) {
    float s = 0.f;
#pragma unroll
    for (int cq = 0; cq < NSPLIT; ++cq)
      s += part[((size_t)(blk * NSPLIT + cq) * 18 + o) * 128 + j];
    acc[o] = s;
  }
#pragma unroll
  for (int n = 0; n < NP; ++n) {
    float offx = acc[n] + bp[n];
    float offy = acc[9 + n] + bp[9 + n];
    float px = (float)ii + (float)(n / 3) + offx;
    float py = (float)j  + (float)(n % 3) + offy;
    float f0 = floorf(px), f1 = f0 + 1.f;
    float h0 = floorf(py), h1 = h0 + 1.f;
    int r0 = (int)fminf(fmaxf(f0, 0.f), 127.f);
    int r1 = (int)fminf(fmaxf(f1, 0.f), 127.f);
    int c0 = (int)fminf(fmaxf(h0, 0.f), 127.f);
    int c1 = (int)fminf(fmaxf(h1, 0.f), 127.f);
    float pxc = fminf(fmaxf(px, 0.f), 127.f);
    float pyc = fminf(fmaxf(py, 0.f), 127.f);
    float glt = (1.f + ((float)r0 - pxc)) * (1.f + ((float)c0 - pyc));
    float grb = (1.f - ((float)r1 - pxc)) * (1.f - ((float)c1 - pyc));
    float glb = (1.f + ((float)r0 - pxc)) * (1.f - ((float)c1 - pyc));
    float grt = (1.f - ((float)r1 - pxc)) * (1.f + ((float)c0 - pyc));
    int qb = (c0 < 126) ? c0 : 126;
    bool s0 = (c0 != qb), s1 = (c1 != qb);
    float wA = (s0 ? 0.f : glt) + (s1 ? 0.f : glb);
    float wB = (s0 ? glt : 0.f) + (s1 ? glb : 0.f);
    float wC = (s0 ? 0.f : grt) + (s1 ? 0.f : grb);
    float wD = (s0 ? grt : 0.f) + (s1 ? grb : 0.f);
    int base = (blk * NP + n) * 128 + j;
    midx[base] = r0 | (r1 << 8) | (qb << 16);
    MU mu;
    mu.h = (f16x4){(_Float16)wA, (_Float16)wB, (_Float16)wC, (_Float16)wD};
    mwh[base] = mu.u;
  }
}

// ---------------------------------------------------------------------------
// Fused gather+GEMM, LDS-windowed. Block = (bb, ii-pair): M=256 pixels
// (2 rows x 128 j), N=256 o, K=1280 padded. 8 waves = 2(m) x 4(o);
// wave tile 128m x 64o, acc = 8x4 f32x4 = 128 VGPR.
// Per c16-chunk (8): stage x[16ch][8rows][132pad] fp32 in LDS (coalesced);
// per K32-slice (5/chunk): all waves interp 16 m-frags from LDS-x into
// A[256m][80B-padded rows], barrier, MFMA vs B (gll16 double-buffered).
// Out-of-window rows (P~1e-5) take an exact predicated global fallback.
// ---------------------------------------------------------------------------
__global__ __launch_bounds__(512, 2) void k_gg(
    const float* __restrict__ x, const bf16_t* __restrict__ bt,
    const int* __restrict__ midx, const uint2* __restrict__ mwh,
    float* __restrict__ out)
{
  // XST@0 (67584) | A@67584 (20480, 80B/m-row) | B@88064 (2x16384)
  // | MIDX@120832 (9216) | MWH@130048 (18432)  -> 148480 total
  __shared__ __align__(16) char smem[148480];
  float* xst   = (float*)smem;               // [16ch][8row][132col]
  char*  A_l   = smem + 67584;               // [256 m][80B: 4 k8 x16B + pad]
  char*  B_l   = smem + 88064;               // 2 x [4 k8][256 o][16B]
  int*   midxl = (int*) (smem + 120832);     // [9][256 pix]
  uint2* mwhl  = (uint2*)(smem + 130048);    // [9][256 pix]

  int blk = (blockIdx.x & 7) * 32 + (blockIdx.x >> 3);   // XCD-contiguous
  int bb = blk >> 6, ii0 = (blk & 63) << 1;
  int tid = threadIdx.x;
  int wave = tid >> 6, lane = tid & 63;
  int l15 = lane & 15, quad = lane >> 4;
  int wm = wave >> 2, wo = wave & 3;

  const float* xg = x + (size_t)bb * CIN * HWSZ;

  // ---- meta -> LDS (coalesced over j)
  for (int t = tid; t < 2304; t += 512) {
    int nn = t >> 8, pix = t & 255;
    int iiL = pix >> 7, j = pix & 127;
    int g = ((bb * 128 + ii0 + iiL) * NP + nn) * 128 + j;
    midxl[t] = midx[g];
    mwhl[t]  = mwh[g];
  }

  auto stage_x = [&](int cc) {
    int c0 = cc * 16;
    float4 xv[8];
#pragma unroll
    for (int u8 = 0; u8 < 8; ++u8) {
      int u = tid + u8 * 512;
      int ch = u >> 8, rem = u & 255;
      int row = rem >> 5, c4 = rem & 31;
      int r = ii0 - 2 + row;
      r = min(127, max(0, r));
      xv[u8] = *(const float4*)(xg + (size_t)(c0 + ch) * HWSZ + r * 128 + c4 * 4);
    }
#pragma unroll
    for (int u8 = 0; u8 < 8; ++u8) {
      int u = tid + u8 * 512;
      int ch = u >> 8, rem = u & 255;
      int row = rem >> 5, c4 = rem & 31;
      *(float4*)(xst + ch * 1056 + row * 132 + c4 * 4) = xv[u8];
    }
  };

  auto gll_B = [&](int stn) {
    const char* src = (const char*)bt + (size_t)stn * 16384 + tid * 16;
    char* dst = B_l + (stn & 1) * 16384 + tid * 16;
    gll16(src, dst);
    gll16(src + 8192, dst + 8192);
  };

  stage_x(0);
  gll_B(0);

  f32x4 acc[8][4];
#pragma unroll
  for (int i = 0; i < 8; ++i)
#pragma unroll
    for (int j2 = 0; j2 < 4; ++j2) acc[i][j2] = (f32x4){0.f, 0.f, 0.f, 0.f};

  int st = 0;
#pragma unroll 1
  for (int cc = 0; cc < 8; ++cc) {
    if (cc > 0) { __syncthreads(); stage_x(cc); }
#pragma unroll 1
    for (int s = 0; s < 5; ++s, ++st) {
      __syncthreads();   // x staged / A free (prev MFMA done)

      // ---- interp: build A slice. lane: m=mf*16+l15; quad -> (n,c8-half)
      {
        int nn = 2 * s + (quad >> 1);
        const float* chb = xst + (quad & 1) * (8 * 1056);
#pragma unroll
        for (int f = 0; f < 2; ++f) {
          int pix = (wave * 2 + f) * 16 + l15;
          bf16x8 av = {};
          if (nn < 9) {
            int idx = midxl[nn * 256 + pix];
            MU mu; mu.u = mwhl[nn * 256 + pix];
            float wA = (float)mu.h[0], wB = (float)mu.h[1];
            float wC = (float)mu.h[2], wD = (float)mu.h[3];
            int r0 = idx & 255, r1 = (idx >> 8) & 255, qb = (idx >> 16) & 255;
            int s0 = r0 - (ii0 - 2), s1 = r1 - (ii0 - 2);
            if (((unsigned)s0 < 8u) & ((unsigned)s1 < 8u)) {
              const float* p0 = chb + s0 * 132 + qb;
              const float* p1 = chb + s1 * 132 + qb;
#pragma unroll
              for (int it = 0; it < 8; ++it) {
                av[it] = (bf16_t)(wA * p0[0] + wB * p0[1] + wC * p1[0] + wD * p1[1]);
                p0 += 1056; p1 += 1056;
              }
            } else {   // exact fallback, ~never taken (execz-skipped)
              const float* gb = xg + (size_t)(cc * 16 + (quad & 1) * 8) * HWSZ;
              const float* q0 = gb + r0 * 128 + qb;
              const float* q1 = gb + r1 * 128 + qb;
#pragma unroll
              for (int it = 0; it < 8; ++it) {
                av[it] = (bf16_t)(wA * q0[0] + wB * q0[1] + wC * q1[0] + wD * q1[1]);
                q0 += HWSZ; q1 += HWSZ;
              }
            }
          }
          *(bf16x8*)(A_l + pix * 80 + quad * 16) = av;
        }
      }

      __syncthreads();   // A ready; B(st) drained
      if (st + 1 < NSLICE) gll_B(st + 1);   // lands during MFMA + next interp

      // ---- MFMA: wave (wm,wo) = 128m x 64o
      {
        const char* Bb = B_l + (st & 1) * 16384;
        bf16x8 bfr[4];
#pragma unroll
        for (int of = 0; of < 4; ++of)
          bfr[of] = *(const bf16x8*)(Bb + quad * 4096 + (wo * 64 + of * 16 + l15) * 16);
#pragma unroll
        for (int mf = 0; mf < 8; ++mf) {
          bf16x8 af = *(const bf16x8*)(A_l + (wm * 128 + mf * 16 + l15) * 80 + quad * 16);
#pragma unroll
          for (int of = 0; of < 4; ++of)
            acc[mf][of] = __builtin_amdgcn_mfma_f32_16x16x32_bf16(
                af, bfr[of], acc[mf][of], 0, 0, 0);
        }
      }
    }
  }

  // ---- epilogue: per-wave transpose 16o x 128m pieces, coalesced stores
  __syncthreads();
  float* pw = (float*)smem + wave * 2112;   // 16 x 132 floats per wave
#pragma unroll
  for (int of = 0; of < 4; ++of) {
#pragma unroll
    for (int mf = 0; mf < 8; ++mf)
      *(f32x4*)(pw + l15 * 132 + mf * 16 + quad * 4) = acc[mf][of];
#pragma unroll
    for (int g = 0; g < 8; ++g) {
      int o_loc = (g & 3) * 4 + quad;
      int mcol = (g >> 2) * 64 + l15 * 4;
      f32x4 v = *(const f32x4*)(pw + o_loc * 132 + mcol);
      int o = wo * 64 + of * 16 + o_loc;
      *(f32x4*)(out + ((size_t)(bb * OCH + o) * 128 + (ii0 + wm)) * 128 + mcol) = v;
    }
  }
}

// ---------------------------------------------------------------------------
extern "C" void kernel_launch(void* const* d_in, const int* in_sizes, int n_in,
                              void* d_out, int out_size, void* d_ws, size_t ws_size,
                              hipStream_t stream) {
  const float* x  = (const float*)d_in[0];
  const float* wp = (const float*)d_in[1];
  const float* bp = (const float*)d_in[2];
  const float* wc = (const float*)d_in[3];
  float* out = (float*)d_out;

  bf16_t* BT   = (bf16_t*)d_ws;                                //   655,360 B
  int*    MIDX = (int*)   ((char*)d_ws +  (768u << 10));       // 2,359,296 B
  uint2*  MWH  = (uint2*) ((char*)d_ws + (3072u << 10));       // 4,718,592 B
  float*  PART = (float*) ((char*)d_ws + (8192u << 10));       // 9,437,184 B -> 17.4MB total

  k_bt<<<dim3(160, 8), 256, 0, stream>>>(wc, BT);
  k_conv_part<2><<<1024, 256, 0, stream>>>(x, wp, PART);
  k_meta<2><<<512, 128, 0, stream>>>(PART, bp, MIDX, MWH);
  k_gg<<<256, 512, 0, stream>>>(x, BT, MIDX, MWH, out);
}

// Round 4
// 271.240 us; speedup vs baseline: 1.2927x; 1.0881x over previous
//
#include <hip/hip_runtime.h>
#include <stdint.h>

// Problem constants: B=4, C=128, H=W=128, N=9, OC=256, stride=1
#define CIN   128
#define HWSZ  16384
#define NP    9
#define OCH   256
#define KDIM  1152
#define KP    1280        // padded K for k_gg: k' = (c/16)*160 + n*16 + (c%16)

typedef __bf16 bf16_t;
typedef __bf16 bf16x8 __attribute__((ext_vector_type(8)));
typedef float  f32x4  __attribute__((ext_vector_type(4)));
typedef _Float16 f16x4 __attribute__((ext_vector_type(4)));
union MU { uint2 u; f16x4 h; };
struct __attribute__((packed, aligned(4))) F2 { float x, y; };

// async global->LDS, 16B/lane; LDS dest = wave-uniform base + lane*16.
__device__ __forceinline__ void gll16(const void* g, void* l) {
  __builtin_amdgcn_global_load_lds(
      (const __attribute__((address_space(1))) void*)g,
      (__attribute__((address_space(3))) void*)l, 16, 0, 0);
}

// ---------------------------------------------------------------------------
// B repack for k_gg, padded fragment order: bt[k8'][o][8] bf16, k8' in [0,160).
// ---------------------------------------------------------------------------
__global__ void k_bt(const float* __restrict__ wc, bf16_t* __restrict__ bt) {
  int k8 = blockIdx.x, og = blockIdx.y, tid = threadIdx.x;
  int i = tid & 7, o = og * 32 + (tid >> 3);
  int kp = k8 * 8 + i;
  int cc = kp / 160, rem = kp % 160;
  int n = rem >> 4, ci = rem & 15;
  int c = cc * 16 + ci;
  float v = (n < 9) ? wc[(o * CIN + c) * NP + n] : 0.f;
  bt[(size_t)k8 * 2048 + o * 8 + i] = (bf16_t)v;
}

// ---------------------------------------------------------------------------
// Offset-conv weight split, MFMA B-fragment order.
// wf[hl][chunk36][nf2][lane64][8 bf16]; chunk=(cg,t): k = ch(cg*32+quad*8+i), tap t.
// hl=0: bf16(w); hl=1: bf16(w - bf16(w))  (3-term split -> fp32-grade conv).
// ---------------------------------------------------------------------------
__global__ void k_wf(const float* __restrict__ wc, bf16_t* __restrict__ wf) {
  int chunk = blockIdx.x, nf = blockIdx.y, hl = blockIdx.z;
  int lane = threadIdx.x;
  int l15 = lane & 15, quad = lane >> 4;
  int cg = chunk / 9, t = chunk % 9;
  int o = nf * 16 + l15;
  bf16x8 e;
#pragma unroll
  for (int i = 0; i < 8; ++i) {
    int ch = cg * 32 + quad * 8 + i;
    float w = (o < 18) ? wc[((size_t)o * CIN + ch) * NP + t] : 0.f;
    bf16_t h = (bf16_t)w;
    e[i] = hl ? (bf16_t)(w - (float)h) : h;
  }
  *(bf16x8*)((char*)wf + ((((size_t)hl * 36 + chunk) * 2 + nf) * 64 + lane) * 16) = e;
}

// ---------------------------------------------------------------------------
// Offset conv AS MFMA (3-term bf16 split) + fused bilinear meta.
// Block = (bb, ii-pair): M=256 pix, N=18(pad 32), K=1152 = 4 cg32 x 9 taps.
// xs[4row][132col][32ch] fp32, 144B entries (9x16B -> bank-spread b128 reads).
// Zero-pad OOB (conv semantics). Epilogue: D -> LDS exch -> meta -> midx/mwh.
// ---------------------------------------------------------------------------
__global__ __launch_bounds__(512) void k_off(
    const float* __restrict__ x, const bf16_t* __restrict__ wf,
    const float* __restrict__ bp, int* __restrict__ midx, uint2* __restrict__ mwh)
{
  __shared__ __align__(16) char smem[76032];   // 528 entries x 144B
  int blk = (blockIdx.x & 7) * 32 + (blockIdx.x >> 3);
  int bb = blk >> 6, ii0 = (blk & 63) << 1;
  int tid = threadIdx.x;
  int wave = tid >> 6, lane = tid & 63;
  int l15 = lane & 15, quad = lane >> 4;

  f32x4 acc[2][2];
#pragma unroll
  for (int f = 0; f < 2; ++f)
#pragma unroll
    for (int nf = 0; nf < 2; ++nf) acc[f][nf] = (f32x4){0.f, 0.f, 0.f, 0.f};

#pragma unroll 1
  for (int cg = 0; cg < 4; ++cg) {
    __syncthreads();   // previous cg's fragment reads drained
    for (int u = tid; u < 528; u += 512) {
      int row = u / 132, col = u % 132;
      int gr = ii0 - 1 + row, gc = col - 1;
      bool ok = ((unsigned)gr < 128u) && ((unsigned)gc < 128u);
      const float* gp = x + ((size_t)(bb * CIN + cg * 32)) * HWSZ + gr * 128 + gc;
      float v[32];
#pragma unroll
      for (int ch = 0; ch < 32; ++ch) v[ch] = ok ? gp[(size_t)ch * HWSZ] : 0.f;
#pragma unroll
      for (int q8 = 0; q8 < 8; ++q8)
        *(f32x4*)(smem + (size_t)u * 144 + q8 * 16) =
            (f32x4){v[q8 * 4], v[q8 * 4 + 1], v[q8 * 4 + 2], v[q8 * 4 + 3]};
    }
    __syncthreads();
#pragma unroll
    for (int t = 0; t < 9; ++t) {
      int chunk = cg * 9 + t, dy = t / 3, dx = t % 3;
      const char* wb = (const char*)wf;
      bf16x8 bh0 = *(const bf16x8*)(wb + (((size_t)chunk) * 2 + 0) * 1024 + lane * 16);
      bf16x8 bh1 = *(const bf16x8*)(wb + (((size_t)chunk) * 2 + 1) * 1024 + lane * 16);
      bf16x8 bl0 = *(const bf16x8*)(wb + (((size_t)36 + chunk) * 2 + 0) * 1024 + lane * 16);
      bf16x8 bl1 = *(const bf16x8*)(wb + (((size_t)36 + chunk) * 2 + 1) * 1024 + lane * 16);
#pragma unroll
      for (int f = 0; f < 2; ++f) {
        int m = (wave * 2 + f) * 16 + l15;
        int row = (m >> 7) + dy, col = (m & 127) + dx;
        int ent = row * 132 + col;
        f32x4 xlo = *(const f32x4*)(smem + (size_t)ent * 144 + quad * 32);
        f32x4 xhi = *(const f32x4*)(smem + (size_t)ent * 144 + quad * 32 + 16);
        bf16x8 ah, al;
#pragma unroll
        for (int i = 0; i < 4; ++i) {
          float v0 = xlo[i], v1 = xhi[i];
          bf16_t h0 = (bf16_t)v0, h1 = (bf16_t)v1;
          ah[i] = h0; ah[i + 4] = h1;
          al[i] = (bf16_t)(v0 - (float)h0);
          al[i + 4] = (bf16_t)(v1 - (float)h1);
        }
        acc[f][0] = __builtin_amdgcn_mfma_f32_16x16x32_bf16(ah, bh0, acc[f][0], 0, 0, 0);
        acc[f][0] = __builtin_amdgcn_mfma_f32_16x16x32_bf16(ah, bl0, acc[f][0], 0, 0, 0);
        acc[f][0] = __builtin_amdgcn_mfma_f32_16x16x32_bf16(al, bh0, acc[f][0], 0, 0, 0);
        acc[f][1] = __builtin_amdgcn_mfma_f32_16x16x32_bf16(ah, bh1, acc[f][1], 0, 0, 0);
        acc[f][1] = __builtin_amdgcn_mfma_f32_16x16x32_bf16(ah, bl1, acc[f][1], 0, 0, 0);
        acc[f][1] = __builtin_amdgcn_mfma_f32_16x16x32_bf16(al, bh1, acc[f][1], 0, 0, 0);
      }
    }
  }

  // ---- epilogue: D -> exch -> meta
  __syncthreads();
  float* exch = (float*)smem;   // 256 x 20 floats
#pragma unroll
  for (int f = 0; f < 2; ++f)
#pragma unroll
    for (int nf = 0; nf < 2; ++nf) {
      int o = nf * 16 + l15;
      if (o < 18) {
#pragma unroll
        for (int r = 0; r < 4; ++r) {
          int pix = (wave * 2 + f) * 16 + quad * 4 + r;
          exch[pix * 20 + o] = acc[f][nf][r];
        }
      }
    }
  __syncthreads();
  if (tid < 256) {
    int pix = tid, iiL = pix >> 7, j = pix & 127, ii = ii0 + iiL;
    float a18[18];
#pragma unroll
    for (int o = 0; o < 18; ++o) a18[o] = exch[pix * 20 + o] + bp[o];
#pragma unroll
    for (int n = 0; n < NP; ++n) {
      float offx = a18[n];
      float offy = a18[9 + n];
      float px = (float)ii + (float)(n / 3) + offx;
      float py = (float)j  + (float)(n % 3) + offy;
      float f0 = floorf(px), f1 = f0 + 1.f;
      float h0 = floorf(py), h1 = h0 + 1.f;
      int r0 = (int)fminf(fmaxf(f0, 0.f), 127.f);
      int r1 = (int)fminf(fmaxf(f1, 0.f), 127.f);
      int c0 = (int)fminf(fmaxf(h0, 0.f), 127.f);
      int c1 = (int)fminf(fmaxf(h1, 0.f), 127.f);
      float pxc = fminf(fmaxf(px, 0.f), 127.f);
      float pyc = fminf(fmaxf(py, 0.f), 127.f);
      float glt = (1.f + ((float)r0 - pxc)) * (1.f + ((float)c0 - pyc));
      float grb = (1.f - ((float)r1 - pxc)) * (1.f - ((float)c1 - pyc));
      float glb = (1.f + ((float)r0 - pxc)) * (1.f - ((float)c1 - pyc));
      float grt = (1.f - ((float)r1 - pxc)) * (1.f + ((float)c0 - pyc));
      int qb = (c0 < 126) ? c0 : 126;
      bool s0 = (c0 != qb), s1 = (c1 != qb);
      float wA = (s0 ? 0.f : glt) + (s1 ? 0.f : glb);
      float wB = (s0 ? glt : 0.f) + (s1 ? glb : 0.f);
      float wC = (s0 ? 0.f : grt) + (s1 ? 0.f : grb);
      float wD = (s0 ? grt : 0.f) + (s1 ? grb : 0.f);
      int base = ((bb * 128 + ii) * NP + n) * 128 + j;
      midx[base] = r0 | (r1 << 8) | (qb << 16);
      MU mu;
      mu.h = (f16x4){(_Float16)wA, (_Float16)wB, (_Float16)wC, (_Float16)wD};
      mwh[base] = mu.u;
    }
  }
}

// ---------------------------------------------------------------------------
// Fused gather+GEMM. Block = (bb, ii-pair): M=256 pix, N=256 o, K=1280 padded.
// x-window staged as TWO bf16 planes [8row][132col][8ch] (16B entries):
// one interp corner = ONE aligned ds_read_b128 (8 ch), consecutive-col entries
// tile all 32 banks -> conflict-free (round-3 had 64x ds_read_b32 + 30M confl).
// Meta preloaded to regs once. A double-buffered -> 1 barrier/slice.
// ---------------------------------------------------------------------------
__global__ __launch_bounds__(512, 2) void k_gg(
    const float* __restrict__ x, const bf16_t* __restrict__ bt,
    const int* __restrict__ midx, const uint2* __restrict__ mwh,
    float* __restrict__ out)
{
  // XP0@0(16912) XP1@16912 | A0@33824 A1@54304 (256x80B each) | B@74784(2x16384)
  // | midxl@107552(9216) | mwhl@116768(18432) -> 135200
  __shared__ __align__(16) char smem[135200];
  char*  Bl    = smem + 74784;
  int*   midxl = (int*)  (smem + 107552);
  uint2* mwhl  = (uint2*)(smem + 116768);

  int blk = (blockIdx.x & 7) * 32 + (blockIdx.x >> 3);
  int bb = blk >> 6, ii0 = (blk & 63) << 1;
  int tid = threadIdx.x;
  int wave = tid >> 6, lane = tid & 63;
  int l15 = lane & 15, quad = lane >> 4;
  int wm = wave >> 2, wo = wave & 3;

  const float* xg = x + (size_t)bb * CIN * HWSZ;

  // ---- meta -> LDS (coalesced)
  for (int t = tid; t < 2304; t += 512) {
    int nn = t >> 8, pix = t & 255;
    int iiL = pix >> 7, j = pix & 127;
    int g = ((bb * 128 + ii0 + iiL) * NP + nn) * 128 + j;
    midxl[t] = midx[g];
    mwhl[t]  = mwh[g];
  }

  auto stage_x = [&](int cc) {
    int c0 = cc * 16;
    int row = tid >> 6, cq = tid & 63;    // row wave-uniform; cols cq, cq+64
    int r = min(127, max(0, ii0 - 2 + row));
    const float* gp = xg + (size_t)c0 * HWSZ + r * 128;
    float v0[16], v1[16];
#pragma unroll
    for (int ch = 0; ch < 16; ++ch) {
      v0[ch] = gp[(size_t)ch * HWSZ + cq];
      v1[ch] = gp[(size_t)ch * HWSZ + cq + 64];
    }
    int ent0 = row * 132 + cq;
#pragma unroll
    for (int p = 0; p < 2; ++p) {
      bf16x8 e0, e1;
#pragma unroll
      for (int i = 0; i < 8; ++i) {
        e0[i] = (bf16_t)v0[p * 8 + i];
        e1[i] = (bf16_t)v1[p * 8 + i];
      }
      char* b = smem + p * 16912;
      *(bf16x8*)(b + ent0 * 16)        = e0;
      *(bf16x8*)(b + (ent0 + 64) * 16) = e1;
    }
  };

  auto gll_B = [&](int stn) {
    const char* src = (const char*)bt + (size_t)stn * 16384 + tid * 16;
    char* dst = Bl + (stn & 1) * 16384 + tid * 16;
    gll16(src, dst);
    gll16(src + 8192, dst + 8192);
  };

  stage_x(0);
  gll_B(0);
  __syncthreads();   // meta + stage(0) visible; B(0) drained

  // ---- preload meta to regs (re-used across all 8 cc)
  uint32_t pmi[5][2];
  uint2    pmw[5][2];
#pragma unroll
  for (int s = 0; s < 5; ++s) {
    int nn = 2 * s + (quad >> 1);
#pragma unroll
    for (int f = 0; f < 2; ++f) {
      int pix = (wave * 2 + f) * 16 + l15;
      if (nn < 9) {
        pmi[s][f] = (uint32_t)midxl[nn * 256 + pix];
        pmw[s][f] = mwhl[nn * 256 + pix];
      } else {
        pmi[s][f] = 0xFFFFFFFFu;
        pmw[s][f] = make_uint2(0u, 0u);
      }
    }
  }

  f32x4 acc[8][4];
#pragma unroll
  for (int i = 0; i < 8; ++i)
#pragma unroll
    for (int j2 = 0; j2 < 4; ++j2) acc[i][j2] = (f32x4){0.f, 0.f, 0.f, 0.f};

#pragma unroll 1
  for (int cc = 0; cc < 8; ++cc) {
    if (cc > 0) __syncthreads();   // stage(cc) visible
#pragma unroll
    for (int s = 0; s < 5; ++s) {
      int st = cc * 5 + s;
      char* Abuf = smem + 33824 + (st & 1) * 20480;

      // ---- interp: one b128 per corner (8 ch), 4 corners per fragment
#pragma unroll
      for (int f = 0; f < 2; ++f) {
        int pix = (wave * 2 + f) * 16 + l15;
        bf16x8 av = {};
        uint32_t im = pmi[s][f];
        if (im != 0xFFFFFFFFu) {
          MU mu; mu.u = pmw[s][f];
          float wA = (float)mu.h[0], wB = (float)mu.h[1];
          float wC = (float)mu.h[2], wD = (float)mu.h[3];
          int r0 = im & 255, r1 = (im >> 8) & 255, qb = (im >> 16) & 255;
          int s0 = r0 - ii0 + 2, s1 = r1 - ii0 + 2;
          if (((unsigned)s0 < 8u) & ((unsigned)s1 < 8u)) {
            const char* pb = smem + (quad & 1) * 16912;
            bf16x8 a0 = *(const bf16x8*)(pb + (s0 * 132 + qb) * 16);
            bf16x8 a1 = *(const bf16x8*)(pb + (s0 * 132 + qb) * 16 + 16);
            bf16x8 b0 = *(const bf16x8*)(pb + (s1 * 132 + qb) * 16);
            bf16x8 b1 = *(const bf16x8*)(pb + (s1 * 132 + qb) * 16 + 16);
#pragma unroll
            for (int it = 0; it < 8; ++it)
              av[it] = (bf16_t)(wA * (float)a0[it] + wB * (float)a1[it] +
                                wC * (float)b0[it] + wD * (float)b1[it]);
          } else {   // exact fp32 fallback, ~never taken
            const float* gb = xg + (size_t)(cc * 16 + (quad & 1) * 8) * HWSZ;
            const float* q0 = gb + r0 * 128 + qb;
            const float* q1 = gb + r1 * 128 + qb;
#pragma unroll
            for (int it = 0; it < 8; ++it) {
              av[it] = (bf16_t)(wA * q0[0] + wB * q0[1] + wC * q1[0] + wD * q1[1]);
              q0 += HWSZ; q1 += HWSZ;
            }
          }
        }
        *(bf16x8*)(Abuf + pix * 80 + quad * 16) = av;
      }

      __syncthreads();   // A(st) ready; B(st) drained; prev A-reads drained
      if (st < 39) gll_B(st + 1);   // lands under MFMA + next interp

      // ---- MFMA: wave (wm,wo) = 128m x 64o
      {
        const char* Bb = Bl + (st & 1) * 16384;
        bf16x8 bfr[4];
#pragma unroll
        for (int of = 0; of < 4; ++of)
          bfr[of] = *(const bf16x8*)(Bb + quad * 4096 + (wo * 64 + of * 16 + l15) * 16);
#pragma unroll
        for (int mf = 0; mf < 8; ++mf) {
          bf16x8 af = *(const bf16x8*)(Abuf + (wm * 128 + mf * 16 + l15) * 80 + quad * 16);
#pragma unroll
          for (int of = 0; of < 4; ++of)
            acc[mf][of] = __builtin_amdgcn_mfma_f32_16x16x32_bf16(
                af, bfr[of], acc[mf][of], 0, 0, 0);
        }
      }
    }
    if (cc < 7) stage_x(cc + 1);   // prev interp reads drained at slice barrier
  }

  // ---- epilogue: per-wave transpose 16o x 128m pieces, coalesced stores
  __syncthreads();
  float* pw = (float*)smem + wave * 2112;   // 16 x 132 floats per wave
#pragma unroll
  for (int of = 0; of < 4; ++of) {
#pragma unroll
    for (int mf = 0; mf < 8; ++mf)
      *(f32x4*)(pw + l15 * 132 + mf * 16 + quad * 4) = acc[mf][of];
#pragma unroll
    for (int g = 0; g < 8; ++g) {
      int o_loc = (g & 3) * 4 + quad;
      int mcol = (g >> 2) * 64 + l15 * 4;
      f32x4 v = *(const f32x4*)(pw + o_loc * 132 + mcol);
      int o = wo * 64 + of * 16 + o_loc;
      *(f32x4*)(out + ((size_t)(bb * OCH + o) * 128 + (ii0 + wm)) * 128 + mcol) = v;
    }
  }
}

// ---------------------------------------------------------------------------
extern "C" void kernel_launch(void* const* d_in, const int* in_sizes, int n_in,
                              void* d_out, int out_size, void* d_ws, size_t ws_size,
                              hipStream_t stream) {
  const float* x  = (const float*)d_in[0];
  const float* wp = (const float*)d_in[1];
  const float* bp = (const float*)d_in[2];
  const float* wc = (const float*)d_in[3];
  float* out = (float*)d_out;

  bf16_t* BT   = (bf16_t*)d_ws;                              //   655,360 B
  bf16_t* WF   = (bf16_t*)((char*)d_ws + 671744);            //   147,456 B
  int*    MIDX = (int*)   ((char*)d_ws + (1u << 20));        // 2,359,296 B
  uint2*  MWH  = (uint2*) ((char*)d_ws + (4u << 20));        // 4,718,592 B -> 8.5MB

  k_bt<<<dim3(160, 8), 256, 0, stream>>>(wc, BT);
  k_wf<<<dim3(36, 2, 2), 64, 0, stream>>>(wp, WF);
  k_off<<<256, 512, 0, stream>>>(x, WF, bp, MIDX, MWH);
  k_gg<<<256, 512, 0, stream>>>(x, BT, MIDX, MWH, out);
}

// Round 5
// 192.111 us; speedup vs baseline: 1.8252x; 1.4119x over previous
//
#include <hip/hip_runtime.h>
#include <stdint.h>

// Problem constants: B=4, C=128, H=W=128, N=9, OC=256, stride=1
#define CIN   128
#define HWSZ  16384
#define NP    9
#define OCH   256
#define KDIM  1152
#define KP    1280        // padded K for k_gg: k' = (c/16)*160 + n*16 + (c%16)

typedef __bf16 bf16_t;
typedef __bf16 bf16x8 __attribute__((ext_vector_type(8)));
typedef float  f32x4  __attribute__((ext_vector_type(4)));
typedef _Float16 f16x4 __attribute__((ext_vector_type(4)));
union MU { uint2 u; f16x4 h; };
struct __attribute__((packed, aligned(4))) F2 { float x, y; };

// async global->LDS, 16B/lane; LDS dest = wave-uniform base + lane*16.
__device__ __forceinline__ void gll16(const void* g, void* l) {
  __builtin_amdgcn_global_load_lds(
      (const __attribute__((address_space(1))) void*)g,
      (__attribute__((address_space(3))) void*)l, 16, 0, 0);
}

// ---------------------------------------------------------------------------
// B repack for k_gg, padded fragment order: bt[k8'][o][8] bf16, k8' in [0,160).
// ---------------------------------------------------------------------------
__global__ void k_bt(const float* __restrict__ wc, bf16_t* __restrict__ bt) {
  int k8 = blockIdx.x, og = blockIdx.y, tid = threadIdx.x;
  int i = tid & 7, o = og * 32 + (tid >> 3);
  int kp = k8 * 8 + i;
  int cc = kp / 160, rem = kp % 160;
  int n = rem >> 4, ci = rem & 15;
  int c = cc * 16 + ci;
  float v = (n < 9) ? wc[(o * CIN + c) * NP + n] : 0.f;
  bt[(size_t)k8 * 2048 + o * 8 + i] = (bf16_t)v;
}

// ---------------------------------------------------------------------------
// Offset-conv weight split, MFMA B-fragment order.
// wf[hl][chunk36][nf2][lane64][8 bf16]; chunk=(cg,t): k = ch(cg*32+quad*8+i), tap t.
// hl=0: bf16(w); hl=1: bf16(w - bf16(w))  (3-term split -> fp32-grade conv).
// ---------------------------------------------------------------------------
__global__ void k_wf(const float* __restrict__ wc, bf16_t* __restrict__ wf) {
  int chunk = blockIdx.x, nf = blockIdx.y, hl = blockIdx.z;
  int lane = threadIdx.x;
  int l15 = lane & 15, quad = lane >> 4;
  int cg = chunk / 9, t = chunk % 9;
  int o = nf * 16 + l15;
  bf16x8 e;
#pragma unroll
  for (int i = 0; i < 8; ++i) {
    int ch = cg * 32 + quad * 8 + i;
    float w = (o < 18) ? wc[((size_t)o * CIN + ch) * NP + t] : 0.f;
    bf16_t h = (bf16_t)w;
    e[i] = hl ? (bf16_t)(w - (float)h) : h;
  }
  *(bf16x8*)((char*)wf + ((((size_t)hl * 36 + chunk) * 2 + nf) * 64 + lane) * 16) = e;
}

// ---------------------------------------------------------------------------
// Offset conv AS MFMA (3-term bf16 split) + fused bilinear meta.
// Block = (bb, ii-pair): M=256 pix, N=18(pad 32), K=1152 = 4 cg32 x 9 taps.
// xs[4row][132col][32ch] fp32, 144B entries. Zero-pad OOB (conv semantics).
// Epilogue: D -> LDS exch -> meta -> midx/mwh.
// ---------------------------------------------------------------------------
__global__ __launch_bounds__(512) void k_off(
    const float* __restrict__ x, const bf16_t* __restrict__ wf,
    const float* __restrict__ bp, int* __restrict__ midx, uint2* __restrict__ mwh)
{
  __shared__ __align__(16) char smem[76032];   // 528 entries x 144B
  int blk = (blockIdx.x & 7) * 32 + (blockIdx.x >> 3);
  int bb = blk >> 6, ii0 = (blk & 63) << 1;
  int tid = threadIdx.x;
  int wave = tid >> 6, lane = tid & 63;
  int l15 = lane & 15, quad = lane >> 4;

  f32x4 acc[2][2];
#pragma unroll
  for (int f = 0; f < 2; ++f)
#pragma unroll
    for (int nf = 0; nf < 2; ++nf) acc[f][nf] = (f32x4){0.f, 0.f, 0.f, 0.f};

#pragma unroll 1
  for (int cg = 0; cg < 4; ++cg) {
    __syncthreads();   // previous cg's fragment reads drained
    for (int u = tid; u < 528; u += 512) {
      int row = u / 132, col = u % 132;
      int gr = ii0 - 1 + row, gc = col - 1;
      bool ok = ((unsigned)gr < 128u) && ((unsigned)gc < 128u);
      const float* gp = x + ((size_t)(bb * CIN + cg * 32)) * HWSZ + gr * 128 + gc;
      float v[32];
#pragma unroll
      for (int ch = 0; ch < 32; ++ch) v[ch] = ok ? gp[(size_t)ch * HWSZ] : 0.f;
#pragma unroll
      for (int q8 = 0; q8 < 8; ++q8)
        *(f32x4*)(smem + (size_t)u * 144 + q8 * 16) =
            (f32x4){v[q8 * 4], v[q8 * 4 + 1], v[q8 * 4 + 2], v[q8 * 4 + 3]};
    }
    __syncthreads();
#pragma unroll
    for (int t = 0; t < 9; ++t) {
      int chunk = cg * 9 + t, dy = t / 3, dx = t % 3;
      const char* wb = (const char*)wf;
      bf16x8 bh0 = *(const bf16x8*)(wb + (((size_t)chunk) * 2 + 0) * 1024 + lane * 16);
      bf16x8 bh1 = *(const bf16x8*)(wb + (((size_t)chunk) * 2 + 1) * 1024 + lane * 16);
      bf16x8 bl0 = *(const bf16x8*)(wb + (((size_t)36 + chunk) * 2 + 0) * 1024 + lane * 16);
      bf16x8 bl1 = *(const bf16x8*)(wb + (((size_t)36 + chunk) * 2 + 1) * 1024 + lane * 16);
#pragma unroll
      for (int f = 0; f < 2; ++f) {
        int m = (wave * 2 + f) * 16 + l15;
        int row = (m >> 7) + dy, col = (m & 127) + dx;
        int ent = row * 132 + col;
        f32x4 xlo = *(const f32x4*)(smem + (size_t)ent * 144 + quad * 32);
        f32x4 xhi = *(const f32x4*)(smem + (size_t)ent * 144 + quad * 32 + 16);
        bf16x8 ah, al;
#pragma unroll
        for (int i = 0; i < 4; ++i) {
          float v0 = xlo[i], v1 = xhi[i];
          bf16_t h0 = (bf16_t)v0, h1 = (bf16_t)v1;
          ah[i] = h0; ah[i + 4] = h1;
          al[i] = (bf16_t)(v0 - (float)h0);
          al[i + 4] = (bf16_t)(v1 - (float)h1);
        }
        acc[f][0] = __builtin_amdgcn_mfma_f32_16x16x32_bf16(ah, bh0, acc[f][0], 0, 0, 0);
        acc[f][0] = __builtin_amdgcn_mfma_f32_16x16x32_bf16(ah, bl0, acc[f][0], 0, 0, 0);
        acc[f][0] = __builtin_amdgcn_mfma_f32_16x16x32_bf16(al, bh0, acc[f][0], 0, 0, 0);
        acc[f][1] = __builtin_amdgcn_mfma_f32_16x16x32_bf16(ah, bh1, acc[f][1], 0, 0, 0);
        acc[f][1] = __builtin_amdgcn_mfma_f32_16x16x32_bf16(ah, bl1, acc[f][1], 0, 0, 0);
        acc[f][1] = __builtin_amdgcn_mfma_f32_16x16x32_bf16(al, bh1, acc[f][1], 0, 0, 0);
      }
    }
  }

  // ---- epilogue: D -> exch -> meta
  __syncthreads();
  float* exch = (float*)smem;   // 256 x 20 floats
#pragma unroll
  for (int f = 0; f < 2; ++f)
#pragma unroll
    for (int nf = 0; nf < 2; ++nf) {
      int o = nf * 16 + l15;
      if (o < 18) {
#pragma unroll
        for (int r = 0; r < 4; ++r) {
          int pix = (wave * 2 + f) * 16 + quad * 4 + r;
          exch[pix * 20 + o] = acc[f][nf][r];
        }
      }
    }
  __syncthreads();
  if (tid < 256) {
    int pix = tid, iiL = pix >> 7, j = pix & 127, ii = ii0 + iiL;
    float a18[18];
#pragma unroll
    for (int o = 0; o < 18; ++o) a18[o] = exch[pix * 20 + o] + bp[o];
#pragma unroll
    for (int n = 0; n < NP; ++n) {
      float offx = a18[n];
      float offy = a18[9 + n];
      float px = (float)ii + (float)(n / 3) + offx;
      float py = (float)j  + (float)(n % 3) + offy;
      float f0 = floorf(px), f1 = f0 + 1.f;
      float h0 = floorf(py), h1 = h0 + 1.f;
      int r0 = (int)fminf(fmaxf(f0, 0.f), 127.f);
      int r1 = (int)fminf(fmaxf(f1, 0.f), 127.f);
      int c0 = (int)fminf(fmaxf(h0, 0.f), 127.f);
      int c1 = (int)fminf(fmaxf(h1, 0.f), 127.f);
      float pxc = fminf(fmaxf(px, 0.f), 127.f);
      float pyc = fminf(fmaxf(py, 0.f), 127.f);
      float glt = (1.f + ((float)r0 - pxc)) * (1.f + ((float)c0 - pyc));
      float grb = (1.f - ((float)r1 - pxc)) * (1.f - ((float)c1 - pyc));
      float glb = (1.f + ((float)r0 - pxc)) * (1.f - ((float)c1 - pyc));
      float grt = (1.f - ((float)r1 - pxc)) * (1.f + ((float)c0 - pyc));
      int qb = (c0 < 126) ? c0 : 126;
      bool s0 = (c0 != qb), s1 = (c1 != qb);
      float wA = (s0 ? 0.f : glt) + (s1 ? 0.f : glb);
      float wB = (s0 ? glt : 0.f) + (s1 ? glb : 0.f);
      float wC = (s0 ? 0.f : grt) + (s1 ? 0.f : grb);
      float wD = (s0 ? grt : 0.f) + (s1 ? grb : 0.f);
      int base = ((bb * 128 + ii) * NP + n) * 128 + j;
      midx[base] = r0 | (r1 << 8) | (qb << 16);
      MU mu;
      mu.h = (f16x4){(_Float16)wA, (_Float16)wB, (_Float16)wC, (_Float16)wD};
      mwh[base] = mu.u;
    }
  }
}

// ---------------------------------------------------------------------------
// Fused gather+GEMM. Block = (bb, ii-pair): M=256 pix, N=256 o, K=1280 padded.
// x-window: TWO bf16 planes [8row][132col][8ch] (16B entries) -> one interp
// corner = one aligned ds_read_b128. Meta read per-slice from LDS (NOT
// register-preloaded: round-4's preload + fat stage_x pushed liveness past
// the 128-VGPR budget -> acc spilled to scratch, +190MB/dispatch HBM).
// stage_x processes one 16B entry at a time (8 floats live, not 32).
// ---------------------------------------------------------------------------
__global__ __launch_bounds__(512) void k_gg(
    const float* __restrict__ x, const bf16_t* __restrict__ bt,
    const int* __restrict__ midx, const uint2* __restrict__ mwh,
    float* __restrict__ out)
{
  // XP0@0(16912) XP1@16912 | A0@33824 A1@54304 (256x80B each) | B@74784(2x16384)
  // | midxl@107552(9216) | mwhl@116768(18432) -> 135200
  __shared__ __align__(16) char smem[135200];
  char*  Bl    = smem + 74784;
  int*   midxl = (int*)  (smem + 107552);
  uint2* mwhl  = (uint2*)(smem + 116768);

  int blk = (blockIdx.x & 7) * 32 + (blockIdx.x >> 3);
  int bb = blk >> 6, ii0 = (blk & 63) << 1;
  int tid = threadIdx.x;
  int wave = tid >> 6, lane = tid & 63;
  int l15 = lane & 15, quad = lane >> 4;
  int wm = wave >> 2, wo = wave & 3;

  const float* xg = x + (size_t)bb * CIN * HWSZ;

  // ---- meta -> LDS (coalesced)
  for (int t = tid; t < 2304; t += 512) {
    int nn = t >> 8, pix = t & 255;
    int iiL = pix >> 7, j = pix & 127;
    int g = ((bb * 128 + ii0 + iiL) * NP + nn) * 128 + j;
    midxl[t] = midx[g];
    mwhl[t]  = mwh[g];
  }

  // stage one 16-ch slab of the 8-row window as bf16 entries; low liveness.
  auto stage_x = [&](int cc) {
    int c0 = cc * 16;
#pragma unroll 2
    for (int k = 0; k < 4; ++k) {
      int e = tid + k * 512;          // 0..2047
      int plane = e >> 10;            // c8-half
      int rem = e & 1023;
      int row = rem >> 7, col = rem & 127;
      int r = min(127, max(0, ii0 - 2 + row));
      const float* gp = xg + (size_t)(c0 + plane * 8) * HWSZ + r * 128 + col;
      bf16x8 ev;
#pragma unroll
      for (int i = 0; i < 8; ++i) ev[i] = (bf16_t)gp[(size_t)i * HWSZ];
      *(bf16x8*)(smem + plane * 16912 + (row * 132 + col) * 16) = ev;
    }
  };

  auto gll_B = [&](int stn) {
    const char* src = (const char*)bt + (size_t)stn * 16384 + tid * 16;
    char* dst = Bl + (stn & 1) * 16384 + tid * 16;
    gll16(src, dst);
    gll16(src + 8192, dst + 8192);
  };

  stage_x(0);
  gll_B(0);
  __syncthreads();   // meta + stage(0) visible; B(0) drained

  f32x4 acc[8][4];
#pragma unroll
  for (int i = 0; i < 8; ++i)
#pragma unroll
    for (int j2 = 0; j2 < 4; ++j2) acc[i][j2] = (f32x4){0.f, 0.f, 0.f, 0.f};

#pragma unroll 1
  for (int cc = 0; cc < 8; ++cc) {
    if (cc > 0) __syncthreads();   // stage(cc) visible
#pragma unroll
    for (int s = 0; s < 5; ++s) {
      int st = cc * 5 + s;
      char* Abuf = smem + 33824 + (st & 1) * 20480;

      // ---- interp: one b128 per corner (8 ch), 4 corners per fragment
      int nn = 2 * s + (quad >> 1);
#pragma unroll
      for (int f = 0; f < 2; ++f) {
        int pix = (wave * 2 + f) * 16 + l15;
        bf16x8 av = {};
        if (nn < 9) {
          int im = midxl[nn * 256 + pix];
          MU mu; mu.u = mwhl[nn * 256 + pix];
          float wA = (float)mu.h[0], wB = (float)mu.h[1];
          float wC = (float)mu.h[2], wD = (float)mu.h[3];
          int r0 = im & 255, r1 = (im >> 8) & 255, qb = (im >> 16) & 255;
          int s0 = r0 - ii0 + 2, s1 = r1 - ii0 + 2;
          if (((unsigned)s0 < 8u) & ((unsigned)s1 < 8u)) {
            const char* pb = smem + (quad & 1) * 16912;
            bf16x8 a0 = *(const bf16x8*)(pb + (s0 * 132 + qb) * 16);
            bf16x8 a1 = *(const bf16x8*)(pb + (s0 * 132 + qb) * 16 + 16);
            bf16x8 b0 = *(const bf16x8*)(pb + (s1 * 132 + qb) * 16);
            bf16x8 b1 = *(const bf16x8*)(pb + (s1 * 132 + qb) * 16 + 16);
#pragma unroll
            for (int it = 0; it < 8; ++it)
              av[it] = (bf16_t)(wA * (float)a0[it] + wB * (float)a1[it] +
                                wC * (float)b0[it] + wD * (float)b1[it]);
          } else {   // exact fp32 fallback, ~never taken
            const float* gb = xg + (size_t)(cc * 16 + (quad & 1) * 8) * HWSZ;
            const float* q0 = gb + r0 * 128 + qb;
            const float* q1 = gb + r1 * 128 + qb;
#pragma unroll
            for (int it = 0; it < 8; ++it) {
              av[it] = (bf16_t)(wA * q0[0] + wB * q0[1] + wC * q1[0] + wD * q1[1]);
              q0 += HWSZ; q1 += HWSZ;
            }
          }
        }
        *(bf16x8*)(Abuf + pix * 80 + quad * 16) = av;
      }

      __syncthreads();   // A(st) ready; B(st) drained; prev A-reads drained
      if (st < 39) gll_B(st + 1);   // lands under MFMA + next interp

      // ---- MFMA: wave (wm,wo) = 128m x 64o
      {
        const char* Bb = Bl + (st & 1) * 16384;
        bf16x8 bfr[4];
#pragma unroll
        for (int of = 0; of < 4; ++of)
          bfr[of] = *(const bf16x8*)(Bb + quad * 4096 + (wo * 64 + of * 16 + l15) * 16);
#pragma unroll
        for (int mf = 0; mf < 8; ++mf) {
          bf16x8 af = *(const bf16x8*)(Abuf + (wm * 128 + mf * 16 + l15) * 80 + quad * 16);
#pragma unroll
          for (int of = 0; of < 4; ++of)
            acc[mf][of] = __builtin_amdgcn_mfma_f32_16x16x32_bf16(
                af, bfr[of], acc[mf][of], 0, 0, 0);
        }
      }
    }
    if (cc < 7) stage_x(cc + 1);   // prev interp reads drained at slice barrier
  }

  // ---- epilogue: per-wave transpose 16o x 128m pieces, coalesced stores
  __syncthreads();
  float* pw = (float*)smem + wave * 2112;   // 16 x 132 floats per wave
#pragma unroll
  for (int of = 0; of < 4; ++of) {
#pragma unroll
    for (int mf = 0; mf < 8; ++mf)
      *(f32x4*)(pw + l15 * 132 + mf * 16 + quad * 4) = acc[mf][of];
#pragma unroll
    for (int g = 0; g < 8; ++g) {
      int o_loc = (g & 3) * 4 + quad;
      int mcol = (g >> 2) * 64 + l15 * 4;
      f32x4 v = *(const f32x4*)(pw + o_loc * 132 + mcol);
      int o = wo * 64 + of * 16 + o_loc;
      *(f32x4*)(out + ((size_t)(bb * OCH + o) * 128 + (ii0 + wm)) * 128 + mcol) = v;
    }
  }
}

// ---------------------------------------------------------------------------
extern "C" void kernel_launch(void* const* d_in, const int* in_sizes, int n_in,
                              void* d_out, int out_size, void* d_ws, size_t ws_size,
                              hipStream_t stream) {
  const float* x  = (const float*)d_in[0];
  const float* wp = (const float*)d_in[1];
  const float* bp = (const float*)d_in[2];
  const float* wc = (const float*)d_in[3];
  float* out = (float*)d_out;

  bf16_t* BT   = (bf16_t*)d_ws;                              //   655,360 B
  bf16_t* WF   = (bf16_t*)((char*)d_ws + 671744);            //   147,456 B
  int*    MIDX = (int*)   ((char*)d_ws + (1u << 20));        // 2,359,296 B
  uint2*  MWH  = (uint2*) ((char*)d_ws + (4u << 20));        // 4,718,592 B -> 8.5MB

  k_bt<<<dim3(160, 8), 256, 0, stream>>>(wc, BT);
  k_wf<<<dim3(36, 2, 2), 64, 0, stream>>>(wp, WF);
  k_off<<<256, 512, 0, stream>>>(x, WF, bp, MIDX, MWH);
  k_gg<<<256, 512, 0, stream>>>(x, BT, MIDX, MWH, out);
}